// Round 1
// baseline (404.352 us; speedup 1.0000x reference)
//
#include <hip/hip_runtime.h>
#include <math.h>

#define BATCH 8
#define SQ 2048
#define SK 2048
#define DD 512
#define DV 512

// ---------------------------------------------------------------------------
// Kernel 1: M[b] = (K[b]^T @ V[b]) * (1/sqrt(DD));   M: [BATCH, DD, DV] fp32
// K: [B, SK, DD] row-major, V: [B, SK, DV] row-major.
// 64x64 output tile per block, 256 threads, 4x4 per-thread register tile,
// K-loop chunk of 16 staged in LDS. Both staging loads are coalesced
// (contiguous along the fast dim of K and V).
// ---------------------------------------------------------------------------
__global__ __launch_bounds__(256) void ktv_kernel(const float* __restrict__ Kp,
                                                  const float* __restrict__ Vp,
                                                  float* __restrict__ Mp) {
    const int b  = blockIdx.z;
    const int d0 = blockIdx.x * 64;
    const int v0 = blockIdx.y * 64;
    const float* Kb = Kp + (size_t)b * SK * DD;
    const float* Vb = Vp + (size_t)b * SK * DV;

    __shared__ float Ks[16][64];
    __shared__ float Vs[16][64];

    const int tid = threadIdx.x;
    const int tx = tid & 15;   // 0..15 -> v cols (x4)
    const int ty = tid >> 4;   // 0..15 -> d rows (x4)
    const int lx = tid & 63;   // staging col
    const int ly = tid >> 6;   // staging row base (0..3)

    float acc[4][4] = {};

    for (int t0 = 0; t0 < SK; t0 += 16) {
#pragma unroll
        for (int r = 0; r < 16; r += 4) {
            const int t = t0 + r + ly;
            Ks[r + ly][lx] = Kb[(size_t)t * DD + d0 + lx];
            Vs[r + ly][lx] = Vb[(size_t)t * DV + v0 + lx];
        }
        __syncthreads();
#pragma unroll
        for (int tt = 0; tt < 16; ++tt) {
            float a[4], bv[4];
#pragma unroll
            for (int i = 0; i < 4; ++i) a[i] = Ks[tt][ty * 4 + i];
#pragma unroll
            for (int j = 0; j < 4; ++j) bv[j] = Vs[tt][tx * 4 + j];
#pragma unroll
            for (int i = 0; i < 4; ++i)
#pragma unroll
                for (int j = 0; j < 4; ++j) acc[i][j] += a[i] * bv[j];
        }
        __syncthreads();
    }

    const float scale = 0.04419417382415922f;  // 1/sqrt(512)
    float* Mb = Mp + (size_t)b * DD * DV;
#pragma unroll
    for (int i = 0; i < 4; ++i) {
        float4 o;
        o.x = acc[i][0] * scale;
        o.y = acc[i][1] * scale;
        o.z = acc[i][2] * scale;
        o.w = acc[i][3] * scale;
        *(float4*)&Mb[(size_t)(d0 + ty * 4 + i) * DV + v0 + tx * 4] = o;
    }
}

// ---------------------------------------------------------------------------
// Kernel 2: X[b] = Q[b] @ M[b];   X: [B, SQ, DV] fp32 written to d_out.
// Q: [B, SQ, DD]. Same 64x64 / 4x4 structure; Q tile staged transposed-ish
// into LDS with +1 padding to avoid stride-16 bank conflicts on reads.
// ---------------------------------------------------------------------------
__global__ __launch_bounds__(256) void qm_kernel(const float* __restrict__ Qp,
                                                 const float* __restrict__ Mp,
                                                 float* __restrict__ Xp) {
    const int b  = blockIdx.z;
    const int q0 = blockIdx.x * 64;
    const int v0 = blockIdx.y * 64;
    const float* Qb = Qp + (size_t)b * SQ * DD;
    const float* Mb = Mp + (size_t)b * DD * DV;

    __shared__ float Qs[64][17];   // [q-row][k], padded
    __shared__ float Ms[16][64];   // [k][v-col]

    const int tid = threadIdx.x;
    const int tx = tid & 15;   // v cols (x4)
    const int ty = tid >> 4;   // q rows (x4)
    const int lx = tid & 63;
    const int ly = tid >> 6;
    const int qr = tid >> 4;   // 0..15 q-row for staging
    const int qk = tid & 15;   // 0..15 k for staging

    float acc[4][4] = {};

    for (int k0 = 0; k0 < DD; k0 += 16) {
#pragma unroll
        for (int r = 0; r < 64; r += 16) {
            Qs[r + qr][qk] = Qb[(size_t)(q0 + r + qr) * DD + k0 + qk];
        }
#pragma unroll
        for (int r = 0; r < 16; r += 4) {
            Ms[r + ly][lx] = Mb[(size_t)(k0 + r + ly) * DV + v0 + lx];
        }
        __syncthreads();
#pragma unroll
        for (int tt = 0; tt < 16; ++tt) {
            float a[4], bv[4];
#pragma unroll
            for (int i = 0; i < 4; ++i) a[i] = Qs[ty * 4 + i][tt];
#pragma unroll
            for (int j = 0; j < 4; ++j) bv[j] = Ms[tt][tx * 4 + j];
#pragma unroll
            for (int i = 0; i < 4; ++i)
#pragma unroll
                for (int j = 0; j < 4; ++j) acc[i][j] += a[i] * bv[j];
        }
        __syncthreads();
    }

    float* Xb = Xp + (size_t)b * SQ * DV;
#pragma unroll
    for (int i = 0; i < 4; ++i) {
        float4 o;
        o.x = acc[i][0];
        o.y = acc[i][1];
        o.z = acc[i][2];
        o.w = acc[i][3];
        *(float4*)&Xb[(size_t)(q0 + ty * 4 + i) * DV + v0 + tx * 4] = o;
    }
}

// ---------------------------------------------------------------------------
// Kernel 3: in-place masked softmax over the last dim (DV=512) of d_out.
// mask: feature index j > valid_len[q] -> -1e6 before softmax.
// One wave (64 lanes) per row; 8 elements/lane as two float4s; shuffle
// reductions (wave=64 on gfx950).
// ---------------------------------------------------------------------------
__global__ __launch_bounds__(256) void softmax_kernel(float* __restrict__ X,
                                                      const int* __restrict__ vlen) {
    const int wave = threadIdx.x >> 6;
    const int lane = threadIdx.x & 63;
    const int row  = blockIdx.x * 4 + wave;  // 0 .. B*SQ-1
    const int q    = row & (SQ - 1);
    float* xr = X + (size_t)row * DV;
    const int vl = vlen[q];

    float v[8];
#pragma unroll
    for (int u = 0; u < 2; ++u) {
        const int j0 = u * 256 + lane * 4;
        float4 f = *(const float4*)&xr[j0];
        v[u * 4 + 0] = (j0 + 0 > vl) ? -1.0e6f : f.x;
        v[u * 4 + 1] = (j0 + 1 > vl) ? -1.0e6f : f.y;
        v[u * 4 + 2] = (j0 + 2 > vl) ? -1.0e6f : f.z;
        v[u * 4 + 3] = (j0 + 3 > vl) ? -1.0e6f : f.w;
    }

    float m = v[0];
#pragma unroll
    for (int i = 1; i < 8; ++i) m = fmaxf(m, v[i]);
#pragma unroll
    for (int off = 32; off > 0; off >>= 1) m = fmaxf(m, __shfl_xor(m, off, 64));

    float s = 0.f;
#pragma unroll
    for (int i = 0; i < 8; ++i) {
        v[i] = __expf(v[i] - m);
        s += v[i];
    }
#pragma unroll
    for (int off = 32; off > 0; off >>= 1) s += __shfl_xor(s, off, 64);

    const float inv = 1.0f / s;
#pragma unroll
    for (int u = 0; u < 2; ++u) {
        const int j0 = u * 256 + lane * 4;
        float4 o;
        o.x = v[u * 4 + 0] * inv;
        o.y = v[u * 4 + 1] * inv;
        o.z = v[u * 4 + 2] * inv;
        o.w = v[u * 4 + 3] * inv;
        *(float4*)&xr[j0] = o;
    }
}

extern "C" void kernel_launch(void* const* d_in, const int* in_sizes, int n_in,
                              void* d_out, int out_size, void* d_ws, size_t ws_size,
                              hipStream_t stream) {
    const float* Kp   = (const float*)d_in[0];
    const float* Vp   = (const float*)d_in[1];
    const float* Qp   = (const float*)d_in[2];
    const int*   vlen = (const int*)d_in[3];
    float* out = (float*)d_out;
    float* M   = (float*)d_ws;  // BATCH*DD*DV*4 = 8 MB scratch

    ktv_kernel<<<dim3(DD / 64, DV / 64, BATCH), 256, 0, stream>>>(Kp, Vp, M);
    qm_kernel<<<dim3(SQ / 64, DV / 64, BATCH), 256, 0, stream>>>(Qp, M, out);
    softmax_kernel<<<dim3(BATCH * SQ / 4), 256, 0, stream>>>(out, vlen);
}

// Round 3
// 211.172 us; speedup vs baseline: 1.9148x; 1.9148x over previous
//
#include <hip/hip_runtime.h>
#include <math.h>

#define BATCH 8
#define SQ 2048
#define SK 2048
#define DD 512
#define DV 512

typedef short bf16x8_t __attribute__((ext_vector_type(8)));
typedef float f32x4_t __attribute__((ext_vector_type(4)));

// RTNE fp32 -> bf16 (bit pattern), and exact bf16 -> fp32
__device__ __forceinline__ unsigned short f2bf(float x) {
    unsigned int u = __builtin_bit_cast(unsigned int, x);
    u += 0x7FFFu + ((u >> 16) & 1u);
    return (unsigned short)(u >> 16);
}
__device__ __forceinline__ float bf2f(unsigned short h) {
    return __builtin_bit_cast(float, ((unsigned int)h) << 16);
}

// ---------------------------------------------------------------------------
// Kernel 1: fp32 partials of K^T V (un-scaled), t-split by 4.
// Mpart layout: [ts(4)][b(8)][d(512)][v(512)] fp32  == 32 MB, lives in d_out.
// Per block: 128(d) x 128(v) tile over a 512-long t-range, BK=32.
// Both operands staged t-transposed into LDS as bf16 hi/lo with XOR-swizzled
// 16B chunks (chunk = kq ^ ((row>>2)&3)) so ds_read_b128 frag loads are ~2-way.
// 3-term split MFMA: Kh*Vh + Kh*Vl + Kl*Vh.
// ---------------------------------------------------------------------------
__global__ __launch_bounds__(256) void ktv_mfma(const float* __restrict__ Kp,
                                                const float* __restrict__ Vp,
                                                float* __restrict__ Mpart) {
    const int b  = blockIdx.z & 7;
    const int ts = blockIdx.z >> 3;
    const int d0 = blockIdx.x * 128;
    const int v0 = blockIdx.y * 128;
    const float* Kb = Kp + (size_t)b * SK * DD;
    const float* Vb = Vp + (size_t)b * SK * DV;

    __shared__ __align__(16) unsigned short Kh[4096], Kl[4096], Vh[4096], Vl[4096];

    const int tid  = threadIdx.x;
    const int lane = tid & 63;
    const int w    = tid >> 6;
    const int wd   = (w & 1) * 64;
    const int wv   = (w >> 1) * 64;
    const int uu   = tid >> 5;   // 0..7  (t-pair selector)
    const int xx   = tid & 31;   // d/v column selector

    f32x4_t acc[4][4];
#pragma unroll
    for (int i = 0; i < 4; ++i)
#pragma unroll
        for (int j = 0; j < 4; ++j) acc[i][j] = (f32x4_t){0.f, 0.f, 0.f, 0.f};

    const int tb = ts * 512;
    for (int t0 = 0; t0 < 512; t0 += 32) {
        // ---- stage K,V tiles (32 t x 128 cols), transposed into LDS ----
#pragma unroll
        for (int p = 0; p < 2; ++p) {
            const int t    = 16 * p + 2 * uu;   // even local t
            const int ch_t = t >> 3;            // k-quad index
            const int te   = t & 7;             // element within chunk (even)
            const size_t gr = (size_t)(tb + t0 + t);
#pragma unroll
            for (int c = 0; c < 4; ++c) {
                const int d   = xx + 32 * c;
                const int off = d * 32 + ((ch_t ^ ((d >> 2) & 3)) << 3) + te;
                {
                    const float f0 = Kb[gr * DD + d0 + d];          // FIX: + d0
                    const float f1 = Kb[(gr + 1) * DD + d0 + d];    // FIX: + d0
                    const unsigned short h0 = f2bf(f0), h1 = f2bf(f1);
                    const unsigned short l0 = f2bf(f0 - bf2f(h0));
                    const unsigned short l1 = f2bf(f1 - bf2f(h1));
                    *(unsigned int*)(Kh + off) = (unsigned int)h0 | ((unsigned int)h1 << 16);
                    *(unsigned int*)(Kl + off) = (unsigned int)l0 | ((unsigned int)l1 << 16);
                }
                {
                    const float f0 = Vb[gr * DV + v0 + d];          // FIX: + v0
                    const float f1 = Vb[(gr + 1) * DV + v0 + d];    // FIX: + v0
                    const unsigned short h0 = f2bf(f0), h1 = f2bf(f1);
                    const unsigned short l0 = f2bf(f0 - bf2f(h0));
                    const unsigned short l1 = f2bf(f1 - bf2f(h1));
                    *(unsigned int*)(Vh + off) = (unsigned int)h0 | ((unsigned int)h1 << 16);
                    *(unsigned int*)(Vl + off) = (unsigned int)l0 | ((unsigned int)l1 << 16);
                }
            }
        }
        __syncthreads();

        // ---- MFMA: D[d][v] += K^T V over this 32-chunk of t ----
        const int kq = lane >> 4;
        const int mr = lane & 15;
        bf16x8_t ah[4], al_[4];
#pragma unroll
        for (int tm = 0; tm < 4; ++tm) {
            const int row = wd + tm * 16 + mr;
            const int off = row * 32 + ((kq ^ ((row >> 2) & 3)) << 3);
            ah[tm]  = *(const bf16x8_t*)(Kh + off);
            al_[tm] = *(const bf16x8_t*)(Kl + off);
        }
#pragma unroll
        for (int tn = 0; tn < 4; ++tn) {
            const int row = wv + tn * 16 + mr;
            const int off = row * 32 + ((kq ^ ((row >> 2) & 3)) << 3);
            const bf16x8_t bh = *(const bf16x8_t*)(Vh + off);
            const bf16x8_t bl = *(const bf16x8_t*)(Vl + off);
#pragma unroll
            for (int tm = 0; tm < 4; ++tm) {
                acc[tm][tn] = __builtin_amdgcn_mfma_f32_16x16x32_bf16(ah[tm], bh, acc[tm][tn], 0, 0, 0);
                acc[tm][tn] = __builtin_amdgcn_mfma_f32_16x16x32_bf16(ah[tm], bl, acc[tm][tn], 0, 0, 0);
                acc[tm][tn] = __builtin_amdgcn_mfma_f32_16x16x32_bf16(al_[tm], bh, acc[tm][tn], 0, 0, 0);
            }
        }
        __syncthreads();
    }

    // epilogue: write fp32 partial (C/D layout: col=lane&15, row=quad*4+reg)
    float* Mp = Mpart + (size_t)(ts * 8 + b) * DD * DV;
    const int quad = lane >> 4;
    const int col  = lane & 15;
#pragma unroll
    for (int tm = 0; tm < 4; ++tm)
#pragma unroll
        for (int tn = 0; tn < 4; ++tn)
#pragma unroll
            for (int r = 0; r < 4; ++r) {
                const int d = d0 + wd + tm * 16 + quad * 4 + r;
                const int v = v0 + wv + tn * 16 + col;
                Mp[(size_t)d * DV + v] = acc[tm][tn][r];
            }
}

// ---------------------------------------------------------------------------
// Kernel 2: sum 4 partials, scale by 1/sqrt(512), transpose [d][v]->[v][d],
// emit Mt_hi/Mt_lo bf16 [b][v][d] into d_ws (8 MB total).
// ---------------------------------------------------------------------------
__global__ __launch_bounds__(256) void reduce_cvt(const float* __restrict__ Mpart,
                                                  unsigned short* __restrict__ Mth,
                                                  unsigned short* __restrict__ Mtl) {
    const int b  = blockIdx.z;
    const int d0 = blockIdx.x * 64;
    const int v0 = blockIdx.y * 64;
    __shared__ float T[64][65];
    const int i  = threadIdx.x;
    const int xr = i >> 4;   // 0..15
    const int xc = i & 15;   // 0..15

#pragma unroll
    for (int e = 0; e < 4; ++e) {
        const int dr = e * 16 + xr;
        float sx = 0.f, sy = 0.f, sz = 0.f, sw = 0.f;
#pragma unroll
        for (int sl = 0; sl < 4; ++sl) {
            const float4 f = *(const float4*)&Mpart[((size_t)(sl * 8 + b) * DD + d0 + dr) * DV + v0 + xc * 4];
            sx += f.x; sy += f.y; sz += f.z; sw += f.w;
        }
        T[dr][xc * 4 + 0] = sx;
        T[dr][xc * 4 + 1] = sy;
        T[dr][xc * 4 + 2] = sz;
        T[dr][xc * 4 + 3] = sw;
    }
    __syncthreads();

    const float s = 0.04419417382415922f;  // 1/sqrt(512)
#pragma unroll
    for (int e = 0; e < 4; ++e) {
        const int v = e * 16 + xr;
        unsigned short hh[4], ll[4];
#pragma unroll
        for (int j = 0; j < 4; ++j) {
            const float m = T[xc * 4 + j][v] * s;
            const unsigned short h = f2bf(m);
            hh[j] = h;
            ll[j] = f2bf(m - bf2f(h));
        }
        const size_t o = ((size_t)b * DV + v0 + v) * DD + d0 + xc * 4;
        uint2 hv, lv;
        hv.x = (unsigned int)hh[0] | ((unsigned int)hh[1] << 16);
        hv.y = (unsigned int)hh[2] | ((unsigned int)hh[3] << 16);
        lv.x = (unsigned int)ll[0] | ((unsigned int)ll[1] << 16);
        lv.y = (unsigned int)ll[2] | ((unsigned int)ll[3] << 16);
        *(uint2*)&Mth[o] = hv;
        *(uint2*)&Mtl[o] = lv;
    }
}

// ---------------------------------------------------------------------------
// Kernel 3: X[b] = Q[b] @ M[b] via MFMA 3-term split. B (= Mt) is already
// bf16 hi/lo in k-contiguous layout; Q converted on the fly. 128x128 tiles,
// BK=32, same XOR-swizzled LDS chunks.
// ---------------------------------------------------------------------------
__global__ __launch_bounds__(256) void qm_mfma(const float* __restrict__ Qp,
                                               const unsigned short* __restrict__ Mth,
                                               const unsigned short* __restrict__ Mtl,
                                               float* __restrict__ Xp) {
    const int b  = blockIdx.z;
    const int q0 = blockIdx.x * 128;
    const int v0 = blockIdx.y * 128;
    const float* Qb = Qp + (size_t)b * SQ * DD;
    const unsigned short* Bhg = Mth + (size_t)b * DV * DD;
    const unsigned short* Blg = Mtl + (size_t)b * DV * DD;

    __shared__ __align__(16) unsigned short Qh[4096], Ql[4096], Bh[4096], Bl[4096];

    const int tid  = threadIdx.x;
    const int lane = tid & 63;
    const int w    = tid >> 6;
    const int wq   = (w & 1) * 64;
    const int wv   = (w >> 1) * 64;

    f32x4_t acc[4][4];
#pragma unroll
    for (int i = 0; i < 4; ++i)
#pragma unroll
        for (int j = 0; j < 4; ++j) acc[i][j] = (f32x4_t){0.f, 0.f, 0.f, 0.f};

    for (int k0 = 0; k0 < DD; k0 += 32) {
        // ---- stage Q (fp32 -> bf16 hi/lo), natural [q][k] layout ----
#pragma unroll
        for (int p = 0; p < 4; ++p) {
            const int q  = p * 32 + (tid >> 3);
            const int dc = (tid & 7) * 4;
            const float4 f = *(const float4*)&Qb[(size_t)(q0 + q) * DD + k0 + dc];
            const unsigned short h0 = f2bf(f.x), h1 = f2bf(f.y), h2 = f2bf(f.z), h3 = f2bf(f.w);
            const unsigned short l0 = f2bf(f.x - bf2f(h0)), l1 = f2bf(f.y - bf2f(h1));
            const unsigned short l2 = f2bf(f.z - bf2f(h2)), l3 = f2bf(f.w - bf2f(h3));
            const int off = q * 32 + (((dc >> 3) ^ ((q >> 2) & 3)) << 3) + (dc & 7);
            uint2 hv, lv;
            hv.x = (unsigned int)h0 | ((unsigned int)h1 << 16);
            hv.y = (unsigned int)h2 | ((unsigned int)h3 << 16);
            lv.x = (unsigned int)l0 | ((unsigned int)l1 << 16);
            lv.y = (unsigned int)l2 | ((unsigned int)l3 << 16);
            *(uint2*)(Qh + off) = hv;
            *(uint2*)(Ql + off) = lv;
        }
        // ---- stage B (already bf16 hi/lo, k-contiguous) ----
#pragma unroll
        for (int p = 0; p < 2; ++p) {
            const int v  = p * 64 + (tid >> 2);
            const int kq = tid & 3;
            const int off = v * 32 + ((kq ^ ((v >> 2) & 3)) << 3);
            *(bf16x8_t*)(Bh + off) = *(const bf16x8_t*)&Bhg[(size_t)(v0 + v) * DD + k0 + kq * 8];
            *(bf16x8_t*)(Bl + off) = *(const bf16x8_t*)&Blg[(size_t)(v0 + v) * DD + k0 + kq * 8];
        }
        __syncthreads();

        const int kq = lane >> 4;
        const int mr = lane & 15;
        bf16x8_t ah[4], al_[4];
#pragma unroll
        for (int tm = 0; tm < 4; ++tm) {
            const int row = wq + tm * 16 + mr;
            const int off = row * 32 + ((kq ^ ((row >> 2) & 3)) << 3);
            ah[tm]  = *(const bf16x8_t*)(Qh + off);
            al_[tm] = *(const bf16x8_t*)(Ql + off);
        }
#pragma unroll
        for (int tn = 0; tn < 4; ++tn) {
            const int row = wv + tn * 16 + mr;
            const int off = row * 32 + ((kq ^ ((row >> 2) & 3)) << 3);
            const bf16x8_t bh = *(const bf16x8_t*)(Bh + off);
            const bf16x8_t bl = *(const bf16x8_t*)(Bl + off);
#pragma unroll
            for (int tm = 0; tm < 4; ++tm) {
                acc[tm][tn] = __builtin_amdgcn_mfma_f32_16x16x32_bf16(ah[tm], bh, acc[tm][tn], 0, 0, 0);
                acc[tm][tn] = __builtin_amdgcn_mfma_f32_16x16x32_bf16(ah[tm], bl, acc[tm][tn], 0, 0, 0);
                acc[tm][tn] = __builtin_amdgcn_mfma_f32_16x16x32_bf16(al_[tm], bh, acc[tm][tn], 0, 0, 0);
            }
        }
        __syncthreads();
    }

    float* Xb = Xp + (size_t)b * SQ * DV;
    const int quad = lane >> 4;
    const int col  = lane & 15;
#pragma unroll
    for (int tm = 0; tm < 4; ++tm)
#pragma unroll
        for (int tn = 0; tn < 4; ++tn)
#pragma unroll
            for (int r = 0; r < 4; ++r)
                Xb[(size_t)(q0 + wq + tm * 16 + quad * 4 + r) * DV + v0 + wv + tn * 16 + col] = acc[tm][tn][r];
}

// ---------------------------------------------------------------------------
// Kernel 4: in-place masked softmax over last dim (512). One wave per row.
// ---------------------------------------------------------------------------
__global__ __launch_bounds__(256) void softmax_kernel(float* __restrict__ X,
                                                      const int* __restrict__ vlen) {
    const int wave = threadIdx.x >> 6;
    const int lane = threadIdx.x & 63;
    const int row  = blockIdx.x * 4 + wave;
    const int q    = row & (SQ - 1);
    float* xr = X + (size_t)row * DV;
    const int vl = vlen[q];

    float v[8];
#pragma unroll
    for (int u = 0; u < 2; ++u) {
        const int j0 = u * 256 + lane * 4;
        const float4 f = *(const float4*)&xr[j0];
        v[u * 4 + 0] = (j0 + 0 > vl) ? -1.0e6f : f.x;
        v[u * 4 + 1] = (j0 + 1 > vl) ? -1.0e6f : f.y;
        v[u * 4 + 2] = (j0 + 2 > vl) ? -1.0e6f : f.z;
        v[u * 4 + 3] = (j0 + 3 > vl) ? -1.0e6f : f.w;
    }

    float m = v[0];
#pragma unroll
    for (int i = 1; i < 8; ++i) m = fmaxf(m, v[i]);
#pragma unroll
    for (int off = 32; off > 0; off >>= 1) m = fmaxf(m, __shfl_xor(m, off, 64));

    float s = 0.f;
#pragma unroll
    for (int i = 0; i < 8; ++i) {
        v[i] = __expf(v[i] - m);
        s += v[i];
    }
#pragma unroll
    for (int off = 32; off > 0; off >>= 1) s += __shfl_xor(s, off, 64);

    const float inv = 1.0f / s;
#pragma unroll
    for (int u = 0; u < 2; ++u) {
        const int j0 = u * 256 + lane * 4;
        float4 o;
        o.x = v[u * 4 + 0] * inv;
        o.y = v[u * 4 + 1] * inv;
        o.z = v[u * 4 + 2] * inv;
        o.w = v[u * 4 + 3] * inv;
        *(float4*)&xr[j0] = o;
    }
}

extern "C" void kernel_launch(void* const* d_in, const int* in_sizes, int n_in,
                              void* d_out, int out_size, void* d_ws, size_t ws_size,
                              hipStream_t stream) {
    const float* Kp   = (const float*)d_in[0];
    const float* Vp   = (const float*)d_in[1];
    const float* Qp   = (const float*)d_in[2];
    const int*   vlen = (const int*)d_in[3];
    float* out = (float*)d_out;

    // ws: Mt_hi (4 MB) | Mt_lo (4 MB) -- known-safe 8 MB footprint.
    unsigned short* Mth = (unsigned short*)d_ws;
    unsigned short* Mtl = Mth + (size_t)BATCH * DD * DV;
    // fp32 partials (4 x 8 MB = 32 MB) live in d_out; overwritten by qm later.
    float* Mpart = out;

    ktv_mfma<<<dim3(4, 4, 32), 256, 0, stream>>>(Kp, Vp, Mpart);
    reduce_cvt<<<dim3(8, 8, 8), 256, 0, stream>>>(Mpart, Mth, Mtl);
    qm_mfma<<<dim3(16, 4, 8), 256, 0, stream>>>(Qp, Mth, Mtl, out);
    softmax_kernel<<<dim3(BATCH * SQ / 4), 256, 0, stream>>>(out, vlen);
}

// Round 5
// 208.647 us; speedup vs baseline: 1.9380x; 1.0121x over previous
//
#include <hip/hip_runtime.h>
#include <hip/hip_bf16.h>
#include <math.h>

#define BATCH 8
#define SQ 2048
#define SK 2048
#define DD 512
#define DV 512
#define RP 40   // LDS row pitch in shorts: 32 payload + 8 pad (80 B = 20 banks, gcd(20,32)=4)

typedef short bf16x8_t __attribute__((ext_vector_type(8)));
typedef float f32x4_t __attribute__((ext_vector_type(4)));

// packed RTNE fp32x2 -> bf16x2 (maps to v_cvt_pk_bf16_f32 on gfx950)
__device__ __forceinline__ unsigned int pk_bf16(float a, float b) {
    __hip_bfloat162 h = __float22bfloat162_rn(float2{a, b});
    unsigned int u;
    __builtin_memcpy(&u, &h, 4);   // __hip_bfloat162 isn't trivially copyable; memcpy is the legal bit-extract
    return u;
}
__device__ __forceinline__ float from_hi(unsigned int u) {
    return __builtin_bit_cast(float, u);
}

// ---------------------------------------------------------------------------
// Kernel 1: fp32 partials of K^T V (un-scaled), t-split by 4.
// Mpart layout: [ts(4)][b(8)][d(512)][v(512)] fp32 == 32 MB, lives in d_out.
// 128(d) x 128(v) tile per block over a 512-long t-range, BK=32.
// LDS rows pitch-40 (padded, no XOR): staging b32 writes ~4-way,
// frag ds_read_b128 ~2-way (free). 3-term split: Kh*Vh + Kh*Vl + Kl*Vh.
// ---------------------------------------------------------------------------
__global__ __launch_bounds__(256) void ktv_mfma(const float* __restrict__ Kp,
                                                const float* __restrict__ Vp,
                                                float* __restrict__ Mpart) {
    const int b  = blockIdx.z & 7;
    const int ts = blockIdx.z >> 3;
    const int d0 = blockIdx.x * 128;
    const int v0 = blockIdx.y * 128;
    const float* Kb = Kp + (size_t)b * SK * DD;
    const float* Vb = Vp + (size_t)b * SK * DV;

    __shared__ __align__(16) unsigned short Kh[128 * RP], Kl[128 * RP],
                                            Vh[128 * RP], Vl[128 * RP];

    const int tid  = threadIdx.x;
    const int lane = tid & 63;
    const int w    = tid >> 6;
    const int wd   = (w & 1) * 64;
    const int wv   = (w >> 1) * 64;
    const int uu   = tid >> 5;   // 0..7  (t-pair selector)
    const int xx   = tid & 31;   // d/v column selector (stride-1 for write banking)

    f32x4_t acc[4][4];
#pragma unroll
    for (int i = 0; i < 4; ++i)
#pragma unroll
        for (int j = 0; j < 4; ++j) acc[i][j] = (f32x4_t){0.f, 0.f, 0.f, 0.f};

    const int tb = ts * 512;
    for (int t0 = 0; t0 < 512; t0 += 32) {
        // ---- stage K,V (32 t x 128 cols), transposed into LDS, bf16 hi/lo ----
#pragma unroll
        for (int p = 0; p < 2; ++p) {
            const int t  = 16 * p + 2 * uu;                 // even local t
            const int to = (t >> 3) * 8 + (t & 7);          // within-row offset
            const size_t gr = (size_t)(tb + t0 + t);
#pragma unroll
            for (int c = 0; c < 4; ++c) {
                const int d   = xx + 32 * c;
                const int off = d * RP + to;
                {
                    const float f0 = Kb[gr * DD + d0 + d];
                    const float f1 = Kb[(gr + 1) * DD + d0 + d];
                    const unsigned int h = pk_bf16(f0, f1);
                    const float r0 = f0 - from_hi(h << 16);
                    const float r1 = f1 - from_hi(h & 0xFFFF0000u);
                    *(unsigned int*)(Kh + off) = h;
                    *(unsigned int*)(Kl + off) = pk_bf16(r0, r1);
                }
                {
                    const float f0 = Vb[gr * DV + v0 + d];
                    const float f1 = Vb[(gr + 1) * DV + v0 + d];
                    const unsigned int h = pk_bf16(f0, f1);
                    const float r0 = f0 - from_hi(h << 16);
                    const float r1 = f1 - from_hi(h & 0xFFFF0000u);
                    *(unsigned int*)(Vh + off) = h;
                    *(unsigned int*)(Vl + off) = pk_bf16(r0, r1);
                }
            }
        }
        __syncthreads();

        // ---- MFMA: D[d][v] += K^T V over this 32-chunk of t ----
        const int kq = lane >> 4;
        const int mr = lane & 15;
        bf16x8_t ah[4], al_[4];
#pragma unroll
        for (int tm = 0; tm < 4; ++tm) {
            const int off = (wd + tm * 16 + mr) * RP + kq * 8;
            ah[tm]  = *(const bf16x8_t*)(Kh + off);
            al_[tm] = *(const bf16x8_t*)(Kl + off);
        }
#pragma unroll
        for (int tn = 0; tn < 4; ++tn) {
            const int off = (wv + tn * 16 + mr) * RP + kq * 8;
            const bf16x8_t bh = *(const bf16x8_t*)(Vh + off);
            const bf16x8_t bl = *(const bf16x8_t*)(Vl + off);
#pragma unroll
            for (int tm = 0; tm < 4; ++tm) {
                acc[tm][tn] = __builtin_amdgcn_mfma_f32_16x16x32_bf16(ah[tm], bh, acc[tm][tn], 0, 0, 0);
                acc[tm][tn] = __builtin_amdgcn_mfma_f32_16x16x32_bf16(ah[tm], bl, acc[tm][tn], 0, 0, 0);
                acc[tm][tn] = __builtin_amdgcn_mfma_f32_16x16x32_bf16(al_[tm], bh, acc[tm][tn], 0, 0, 0);
            }
        }
        __syncthreads();
    }

    // epilogue: fp32 partial (C/D layout: col=lane&15, row=quad*4+reg)
    float* Mp = Mpart + (size_t)(ts * 8 + b) * DD * DV;
    const int quad = lane >> 4;
    const int col  = lane & 15;
#pragma unroll
    for (int tm = 0; tm < 4; ++tm)
#pragma unroll
        for (int tn = 0; tn < 4; ++tn)
#pragma unroll
            for (int r = 0; r < 4; ++r) {
                const int d = d0 + wd + tm * 16 + quad * 4 + r;
                const int v = v0 + wv + tn * 16 + col;
                Mp[(size_t)d * DV + v] = acc[tm][tn][r];
            }
}

// ---------------------------------------------------------------------------
// Kernel 2: sum 4 partials, scale by 1/sqrt(512), transpose [d][v]->[v][d],
// emit Mt_hi/Mt_lo bf16 [b][v][d] into d_ws (8 MB total).
// ---------------------------------------------------------------------------
__global__ __launch_bounds__(256) void reduce_cvt(const float* __restrict__ Mpart,
                                                  unsigned short* __restrict__ Mth,
                                                  unsigned short* __restrict__ Mtl) {
    const int b  = blockIdx.z;
    const int d0 = blockIdx.x * 64;
    const int v0 = blockIdx.y * 64;
    __shared__ float T[64][65];
    const int i  = threadIdx.x;
    const int xr = i >> 4;   // 0..15
    const int xc = i & 15;   // 0..15

#pragma unroll
    for (int e = 0; e < 4; ++e) {
        const int dr = e * 16 + xr;
        float sx = 0.f, sy = 0.f, sz = 0.f, sw = 0.f;
#pragma unroll
        for (int sl = 0; sl < 4; ++sl) {
            const float4 f = *(const float4*)&Mpart[((size_t)(sl * 8 + b) * DD + d0 + dr) * DV + v0 + xc * 4];
            sx += f.x; sy += f.y; sz += f.z; sw += f.w;
        }
        T[dr][xc * 4 + 0] = sx;
        T[dr][xc * 4 + 1] = sy;
        T[dr][xc * 4 + 2] = sz;
        T[dr][xc * 4 + 3] = sw;
    }
    __syncthreads();

    const float s = 0.04419417382415922f;  // 1/sqrt(512)
#pragma unroll
    for (int e = 0; e < 4; ++e) {
        const int v = e * 16 + xr;
        float m[4], r[4];
        unsigned int hv[2], lv[2];
#pragma unroll
        for (int j = 0; j < 4; ++j) m[j] = T[xc * 4 + j][v] * s;
#pragma unroll
        for (int j = 0; j < 2; ++j) {
            hv[j] = pk_bf16(m[2 * j], m[2 * j + 1]);
            r[2 * j]     = m[2 * j]     - from_hi(hv[j] << 16);
            r[2 * j + 1] = m[2 * j + 1] - from_hi(hv[j] & 0xFFFF0000u);
            lv[j] = pk_bf16(r[2 * j], r[2 * j + 1]);
        }
        const size_t o = ((size_t)b * DV + v0 + v) * DD + d0 + xc * 4;
        *(uint2*)&Mth[o] = make_uint2(hv[0], hv[1]);
        *(uint2*)&Mtl[o] = make_uint2(lv[0], lv[1]);
    }
}

// ---------------------------------------------------------------------------
// Kernel 3: X[b] = Q[b] @ M[b] via 3-term split MFMA. B (= Mt) pre-split bf16
// k-contiguous; Q converted on the fly (already k-contiguous, no transpose).
// 128x128 tiles, BK=32, pitch-40 padded LDS rows.
// ---------------------------------------------------------------------------
__global__ __launch_bounds__(256) void qm_mfma(const float* __restrict__ Qp,
                                               const unsigned short* __restrict__ Mth,
                                               const unsigned short* __restrict__ Mtl,
                                               float* __restrict__ Xp) {
    const int b  = blockIdx.z;
    const int q0 = blockIdx.x * 128;
    const int v0 = blockIdx.y * 128;
    const float* Qb = Qp + (size_t)b * SQ * DD;
    const unsigned short* Bhg = Mth + (size_t)b * DV * DD;
    const unsigned short* Blg = Mtl + (size_t)b * DV * DD;

    __shared__ __align__(16) unsigned short Qh[128 * RP], Ql[128 * RP],
                                            Bh[128 * RP], Bl[128 * RP];

    const int tid  = threadIdx.x;
    const int lane = tid & 63;
    const int w    = tid >> 6;
    const int wq   = (w & 1) * 64;
    const int wv   = (w >> 1) * 64;

    f32x4_t acc[4][4];
#pragma unroll
    for (int i = 0; i < 4; ++i)
#pragma unroll
        for (int j = 0; j < 4; ++j) acc[i][j] = (f32x4_t){0.f, 0.f, 0.f, 0.f};

    for (int k0 = 0; k0 < DD; k0 += 32) {
        // ---- stage Q (float4 load, packed split), natural [q][k] layout ----
#pragma unroll
        for (int p = 0; p < 4; ++p) {
            const int q  = p * 32 + (tid >> 3);
            const int dc = (tid & 7) * 4;
            const float4 f = *(const float4*)&Qb[(size_t)(q0 + q) * DD + k0 + dc];
            const unsigned int h01 = pk_bf16(f.x, f.y);
            const unsigned int h23 = pk_bf16(f.z, f.w);
            const float r0 = f.x - from_hi(h01 << 16);
            const float r1 = f.y - from_hi(h01 & 0xFFFF0000u);
            const float r2 = f.z - from_hi(h23 << 16);
            const float r3 = f.w - from_hi(h23 & 0xFFFF0000u);
            const int off = q * RP + dc;  // linear within padded row
            *(uint2*)(Qh + off) = make_uint2(h01, h23);
            *(uint2*)(Ql + off) = make_uint2(pk_bf16(r0, r1), pk_bf16(r2, r3));
        }
        // ---- stage B (pre-split bf16, k-contiguous), b128 in/out ----
#pragma unroll
        for (int p = 0; p < 2; ++p) {
            const int v  = p * 64 + (tid >> 2);
            const int kq = tid & 3;
            const int off = v * RP + kq * 8;
            *(bf16x8_t*)(Bh + off) = *(const bf16x8_t*)&Bhg[(size_t)(v0 + v) * DD + k0 + kq * 8];
            *(bf16x8_t*)(Bl + off) = *(const bf16x8_t*)&Blg[(size_t)(v0 + v) * DD + k0 + kq * 8];
        }
        __syncthreads();

        const int kq = lane >> 4;
        const int mr = lane & 15;
        bf16x8_t ah[4], al_[4];
#pragma unroll
        for (int tm = 0; tm < 4; ++tm) {
            const int off = (wq + tm * 16 + mr) * RP + kq * 8;
            ah[tm]  = *(const bf16x8_t*)(Qh + off);
            al_[tm] = *(const bf16x8_t*)(Ql + off);
        }
#pragma unroll
        for (int tn = 0; tn < 4; ++tn) {
            const int off = (wv + tn * 16 + mr) * RP + kq * 8;
            const bf16x8_t bh = *(const bf16x8_t*)(Bh + off);
            const bf16x8_t bl = *(const bf16x8_t*)(Bl + off);
#pragma unroll
            for (int tm = 0; tm < 4; ++tm) {
                acc[tm][tn] = __builtin_amdgcn_mfma_f32_16x16x32_bf16(ah[tm], bh, acc[tm][tn], 0, 0, 0);
                acc[tm][tn] = __builtin_amdgcn_mfma_f32_16x16x32_bf16(ah[tm], bl, acc[tm][tn], 0, 0, 0);
                acc[tm][tn] = __builtin_amdgcn_mfma_f32_16x16x32_bf16(al_[tm], bh, acc[tm][tn], 0, 0, 0);
            }
        }
        __syncthreads();
    }

    float* Xb = Xp + (size_t)b * SQ * DV;
    const int quad = lane >> 4;
    const int col  = lane & 15;
#pragma unroll
    for (int tm = 0; tm < 4; ++tm)
#pragma unroll
        for (int tn = 0; tn < 4; ++tn)
#pragma unroll
            for (int r = 0; r < 4; ++r)
                Xb[(size_t)(q0 + wq + tm * 16 + quad * 4 + r) * DV + v0 + wv + tn * 16 + col] = acc[tm][tn][r];
}

// ---------------------------------------------------------------------------
// Kernel 4: in-place masked softmax over last dim (512). One wave per row.
// ---------------------------------------------------------------------------
__global__ __launch_bounds__(256) void softmax_kernel(float* __restrict__ X,
                                                      const int* __restrict__ vlen) {
    const int wave = threadIdx.x >> 6;
    const int lane = threadIdx.x & 63;
    const int row  = blockIdx.x * 4 + wave;
    const int q    = row & (SQ - 1);
    float* xr = X + (size_t)row * DV;
    const int vl = vlen[q];

    float v[8];
#pragma unroll
    for (int u = 0; u < 2; ++u) {
        const int j0 = u * 256 + lane * 4;
        const float4 f = *(const float4*)&xr[j0];
        v[u * 4 + 0] = (j0 + 0 > vl) ? -1.0e6f : f.x;
        v[u * 4 + 1] = (j0 + 1 > vl) ? -1.0e6f : f.y;
        v[u * 4 + 2] = (j0 + 2 > vl) ? -1.0e6f : f.z;
        v[u * 4 + 3] = (j0 + 3 > vl) ? -1.0e6f : f.w;
    }

    float m = v[0];
#pragma unroll
    for (int i = 1; i < 8; ++i) m = fmaxf(m, v[i]);
#pragma unroll
    for (int off = 32; off > 0; off >>= 1) m = fmaxf(m, __shfl_xor(m, off, 64));

    float s = 0.f;
#pragma unroll
    for (int i = 0; i < 8; ++i) {
        v[i] = __expf(v[i] - m);
        s += v[i];
    }
#pragma unroll
    for (int off = 32; off > 0; off >>= 1) s += __shfl_xor(s, off, 64);

    const float inv = 1.0f / s;
#pragma unroll
    for (int u = 0; u < 2; ++u) {
        const int j0 = u * 256 + lane * 4;
        float4 o;
        o.x = v[u * 4 + 0] * inv;
        o.y = v[u * 4 + 1] * inv;
        o.z = v[u * 4 + 2] * inv;
        o.w = v[u * 4 + 3] * inv;
        *(float4*)&xr[j0] = o;
    }
}

extern "C" void kernel_launch(void* const* d_in, const int* in_sizes, int n_in,
                              void* d_out, int out_size, void* d_ws, size_t ws_size,
                              hipStream_t stream) {
    const float* Kp   = (const float*)d_in[0];
    const float* Vp   = (const float*)d_in[1];
    const float* Qp   = (const float*)d_in[2];
    const int*   vlen = (const int*)d_in[3];
    float* out = (float*)d_out;

    // ws: Mt_hi (4 MB) | Mt_lo (4 MB) -- known-safe 8 MB footprint.
    unsigned short* Mth = (unsigned short*)d_ws;
    unsigned short* Mtl = Mth + (size_t)BATCH * DD * DV;
    // fp32 partials (4 x 8 MB = 32 MB) live in d_out; overwritten by qm later.
    float* Mpart = out;

    ktv_mfma<<<dim3(4, 4, 32), 256, 0, stream>>>(Kp, Vp, Mpart);
    reduce_cvt<<<dim3(8, 8, 8), 256, 0, stream>>>(Mpart, Mth, Mtl);
    qm_mfma<<<dim3(16, 4, 8), 256, 0, stream>>>(Qp, Mth, Mtl, out);
    softmax_kernel<<<dim3(BATCH * SQ / 4), 256, 0, stream>>>(out, vlen);
}